// Round 1
// 1085.752 us; speedup vs baseline: 1.3173x; 1.3173x over previous
//
#include <hip/hip_runtime.h>
#include <cstdint>
#include <cstddef>

// Problem constants
static constexpr int Bn   = 4;
static constexpr int Sn   = 4096;
static constexpr int Hn   = 2048;
static constexpr int CINn = 4096;
static constexpr int COUTn= 4096;
static constexpr int GCn  = 512;    // CIN/G
static constexpr int Kt   = 4;      // conv taps
static constexpr int Mn   = Bn * Sn;   // 16384
static constexpr int SPn  = Sn + 3;    // padded rows per batch (3 zero rows in front)

typedef _Float16 half8 __attribute__((ext_vector_type(8)));
typedef _Float16 half4 __attribute__((ext_vector_type(4)));
typedef float    floatx4 __attribute__((ext_vector_type(4)));

// ---------------- prep kernels ----------------

__global__ void cvt_f32_f16(const float* __restrict__ src, _Float16* __restrict__ dst, int n4) {
    int i = blockIdx.x * blockDim.x + threadIdx.x;
    if (i < n4) {
        float4 v = ((const float4*)src)[i];
        half4 h;
        h[0] = (_Float16)v.x; h[1] = (_Float16)v.y;
        h[2] = (_Float16)v.z; h[3] = (_Float16)v.w;
        ((half4*)dst)[i] = h;
    }
}

// conv_w [COUT, 512, 4] fp32 -> Wc [COUT, k*512 + ci] fp16
__global__ void cvt_convw(const float* __restrict__ src, _Float16* __restrict__ dst) {
    int t = blockIdx.x * blockDim.x + threadIdx.x;   // 0 .. 4096*512
    int co = t >> 9, ci = t & 511;
    float4 v = ((const float4*)src)[(co << 9) + ci]; // src[co][ci][0..3] contiguous
    size_t base = (size_t)co * 2048 + ci;
    dst[base]        = (_Float16)v.x;
    dst[base + 512]  = (_Float16)v.y;
    dst[base + 1024] = (_Float16)v.z;
    dst[base + 1536] = (_Float16)v.w;
}

// zero the 3 leading pad rows of each batch in Hp [B*(S+3), 4096]
__global__ void zero_pads(_Float16* __restrict__ Hp) {
    int t = blockIdx.x * blockDim.x + threadIdx.x;   // 4 * 3*4096 = 49152
    int b = t / (3 * CINn);
    int off = t - b * (3 * CINn);
    Hp[(size_t)b * SPn * CINn + off] = (_Float16)0.f;
}

// ---------------- 256x256 / BK=64 / 8-wave 8-phase GEMM ----------------
// C[m,n] = sum_k A[m,k]*B[n,k]  (B^T layout: K contiguous in both operands)
// MODE 0: stage1  A=Xh[16384,2048]            out: Hp fp16, padded rows, +b_in
// MODE 1: stage2  A=Hp (shifted conv gather)  out: Yh fp16, +conv_b, SiLU
// MODE 2: stage3  A=Yh[16384,4096]            out: fp32, +b_out
//
// LDS: 2 buffers x (A 256x64 + B 256x64) fp16 = 128 KiB. Staging region =
// quarter tile (64 rows x 64 cols) = 1 global_load_lds_dwordx4 per thread.
// Swizzle: col-block(16B) ^= (row&7), applied at the GLOBAL source address
// (gload_lds dest must be linear: wave base + lane*16B); reads de-swizzle.
//
// Per tile t (4 phases, 2 barriers each, counted vmcnt only at P2/P4):
//   P1: ds_read A-half0(8) + B-half0(4); stage (t+1).Aq{1,3} -> buf[nxt]
//   P2: ds_read B-half1(4);              stage (t+2).Aq{0,2} -> buf[cur]; vmcnt(8)
//   P3: ds_read A-half1(8);              stage (t+2).Bq{0,1} -> buf[cur]
//   P4: (regs cached);                   stage (t+2).Bq{2,3} -> buf[cur]; vmcnt(8)
// Safety: each staged region's last ds_read is >=1 barrier-pair earlier
// (Aq02 read P1 / staged P2; Bq read P1-P2 / staged P3-P4; Aq13 read P3 /
// staged next tile's P1). vmcnt(8) retires everything older than the last
// 4 phases' issues => tile t+1 fully landed entering its P1, Aq13 landed
// by its P3. Last two tiles force vmcnt(0) (stages are skipped there).

__device__ __forceinline__ void async16(const void* g, void* l) {
    __builtin_amdgcn_global_load_lds(
        (__attribute__((address_space(1))) void*)(g),
        (__attribute__((address_space(3))) void*)(l),
        16, 0, 0);
}

#define BAR()  __builtin_amdgcn_s_barrier()
#define SB0()  __builtin_amdgcn_sched_barrier(0)
#define WL0()  asm volatile("s_waitcnt lgkmcnt(0)" ::: "memory")
#define WV(n)  asm volatile("s_waitcnt vmcnt(" #n ")" ::: "memory")

template <int MODE>
__global__ __launch_bounds__(512, 2) void gemm8(
    const _Float16* __restrict__ A,
    const _Float16* __restrict__ Bw,
    const float* __restrict__ bias,
    void* __restrict__ outp,
    int Kd, int Ntiles)
{
    __shared__ __align__(16) _Float16 smem[2][2][256 * 64];   // [buf][A/B] 128 KiB

    const int t  = threadIdx.x;
    const int w  = t >> 6;        // wave 0..7
    const int l  = t & 63;
    const int wm = w >> 2;        // 2 wave rows
    const int wn = w & 3;         // 4 wave cols

    // bijective XCD swizzle (nwg % 8 == 0 for all stages)
    const int nwg = (int)gridDim.x;
    const int bid = (int)blockIdx.x;
    const int swz = (bid & 7) * (nwg >> 3) + (bid >> 3);
    const int mt = swz / Ntiles, nt = swz - mt * Ntiles;
    const int m0 = mt * 256, n0 = nt * 256;

    // --- staging addresses: thread t covers row (q*64 + t>>3), swizzled col block
    const int sr  = t >> 3;                        // 0..63
    const int scb = ((t & 7) ^ (sr & 7)) << 3;     // swizzled col, fp16 units
    const _Float16* pa[4];
    const _Float16* pb[4];
    #pragma unroll
    for (int q = 0; q < 4; ++q) {
        int ma = m0 + q * 64 + sr;
        if (MODE == 1) {
            // A row for (m, tap k): b*(S+3) + (s) + k ; col: g*512 + ci
            pa[q] = A + ((size_t)((ma >> 12) * SPn + (ma & 4095)) << 12) + (n0 >> 9) * 512 + scb;
        } else {
            pa[q] = A + (size_t)ma * Kd + scb;
        }
        pb[q] = Bw + (size_t)(n0 + q * 64 + sr) * Kd + scb;
    }
    const int wst = w * 512;      // wave-uniform LDS offset within a region (fp16)

    const int fr = l & 15, quad = l >> 4, sw = fr & 7;

    floatx4 acc[8][4] = {};
    half8 af[4][2];   // current M-half A frags
    half8 bf[4][2];   // all 4 N frags (held across the tile)

    const int NT = Kd >> 6;

#define KADJ(kk) ((MODE == 1) ? ((kk) + (((kk) >> 9) * 3584)) : (kk))
#define STA(b, q, ko) async16(pa[q] + (ko), &smem[b][0][(q) * 4096 + wst])
#define STB(b, q, ko) async16(pb[q] + (ko), &smem[b][1][(q) * 4096 + wst])

#define READ_A(cb, mh) do { \
    _Pragma("unroll") for (int mf = 0; mf < 4; ++mf) \
    _Pragma("unroll") for (int ks = 0; ks < 2; ++ks) { \
        int row = wm * 128 + (mh) * 64 + mf * 16 + fr; \
        af[mf][ks] = *(const half8*)(&smem[cb][0][row * 64 + ((((ks << 2) + quad) ^ sw) << 3)]); \
    } } while (0)

#define READ_B(cb, nh) do { \
    _Pragma("unroll") for (int nf = 0; nf < 2; ++nf) \
    _Pragma("unroll") for (int ks = 0; ks < 2; ++ks) { \
        int row = wn * 64 + ((nh) * 2 + nf) * 16 + fr; \
        bf[(nh) * 2 + nf][ks] = *(const half8*)(&smem[cb][1][row * 64 + ((((ks << 2) + quad) ^ sw) << 3)]); \
    } } while (0)

#define MMA(mh, nh) do { \
    _Pragma("unroll") for (int mf = 0; mf < 4; ++mf) \
    _Pragma("unroll") for (int nf = 0; nf < 2; ++nf) \
    _Pragma("unroll") for (int ks = 0; ks < 2; ++ks) \
        acc[(mh) * 4 + mf][(nh) * 2 + nf] = __builtin_amdgcn_mfma_f32_16x16x32_f16( \
            af[mf][ks], bf[(nh) * 2 + nf][ks], acc[(mh) * 4 + mf][(nh) * 2 + nf], 0, 0, 0); \
    } while (0)

    // --- prologue: tile0 all 8 regions -> buf0; tile1 Aq{0,2}+Bq0-3 -> buf1
    {
        STA(0, 0, 0); STA(0, 1, 0); STA(0, 2, 0); STA(0, 3, 0);
        STB(0, 0, 0); STB(0, 1, 0); STB(0, 2, 0); STB(0, 3, 0);
        const int ka1 = KADJ(64);
        STA(1, 0, ka1); STA(1, 2, ka1);
        STB(1, 0, 64); STB(1, 1, 64); STB(1, 2, 64); STB(1, 3, 64);
        WV(6);                 // tile0's 8 loads retired; tile1's 6 in flight
        BAR();
    }

    for (int tt = 0; tt < NT; ++tt) {
        const int cur = tt & 1, nxt = cur ^ 1;
        const bool s1 = (tt + 1 < NT), s2 = (tt + 2 < NT);
        const int ka1 = KADJ((tt + 1) << 6);
        const int ka2 = KADJ((tt + 2) << 6);
        const int kb2 = (tt + 2) << 6;

        // ---- P1 ----
        READ_A(cur, 0);
        READ_B(cur, 0);
        if (s1) { STA(nxt, 1, ka1); STA(nxt, 3, ka1); }
        SB0(); BAR();
        WL0(); SB0();
        __builtin_amdgcn_s_setprio(1);
        MMA(0, 0);
        __builtin_amdgcn_s_setprio(0);
        SB0(); BAR();

        // ---- P2 ----
        READ_B(cur, 1);
        if (s2) { STA(cur, 0, ka2); STA(cur, 2, ka2); }
        SB0(); BAR();
        WL0(); SB0();
        __builtin_amdgcn_s_setprio(1);
        MMA(0, 1);
        __builtin_amdgcn_s_setprio(0);
        SB0();
        if (s2) { WV(8); } else { WV(0); }
        SB0(); BAR();

        // ---- P3 ----
        READ_A(cur, 1);
        if (s2) { STB(cur, 0, kb2); STB(cur, 1, kb2); }
        SB0(); BAR();
        WL0(); SB0();
        __builtin_amdgcn_s_setprio(1);
        MMA(1, 0);
        __builtin_amdgcn_s_setprio(0);
        SB0(); BAR();

        // ---- P4 ----
        if (s2) { STB(cur, 2, kb2); STB(cur, 3, kb2); }
        SB0(); BAR();
        WL0(); SB0();
        __builtin_amdgcn_s_setprio(1);
        MMA(1, 1);
        __builtin_amdgcn_s_setprio(0);
        SB0();
        if (s2) { WV(8); } else { WV(0); }
        SB0(); BAR();
    }

    // --- epilogue: D[row=(l>>4)*4+r][col=l&15] per 16x16 subtile ---
    #pragma unroll
    for (int nf = 0; nf < 4; ++nf) {
        const int ncol = n0 + wn * 64 + nf * 16 + fr;
        const float bv = bias[ncol];
        #pragma unroll
        for (int mf = 0; mf < 8; ++mf) {
            const int mb = m0 + wm * 128 + mf * 16 + quad * 4;
            #pragma unroll
            for (int r = 0; r < 4; ++r) {
                const int m = mb + r;
                float v = acc[mf][nf][r] + bv;
                if (MODE == 0) {
                    const size_t row = (size_t)((m >> 12) * SPn + 3 + (m & 4095));
                    ((_Float16*)outp)[(row << 12) + ncol] = (_Float16)v;
                } else if (MODE == 1) {
                    v = v * (1.0f / (1.0f + __expf(-v)));   // SiLU
                    ((_Float16*)outp)[((size_t)m << 12) + ncol] = (_Float16)v;
                } else {
                    ((float*)outp)[((size_t)m << 11) + ncol] = v;
                }
            }
        }
    }
#undef KADJ
#undef STA
#undef STB
#undef READ_A
#undef READ_B
#undef MMA
}

// ---------------- launch ----------------

extern "C" void kernel_launch(void* const* d_in, const int* in_sizes, int n_in,
                              void* d_out, int out_size, void* d_ws, size_t ws_size,
                              hipStream_t stream) {
    const float* x      = (const float*)d_in[0];
    const float* W_in   = (const float*)d_in[1];
    const float* b_in   = (const float*)d_in[2];
    const float* conv_w = (const float*)d_in[3];
    const float* conv_b = (const float*)d_in[4];
    const float* W_out  = (const float*)d_in[5];
    const float* b_out  = (const float*)d_in[6];
    float* out = (float*)d_out;

    // workspace layout (bytes) — total ~368 MB
    char* ws = (char*)d_ws;
    _Float16* Xh  = (_Float16*)(ws);                         //  67,108,864  x fp16 [16384,2048]
    _Float16* W1h = (_Float16*)(ws + 67108864);              //  16,777,216  W_in fp16 [4096,2048]
    _Float16* Wch = (_Float16*)(ws + 83886080);              //  16,777,216  conv_w fp16 [4096,2048]
    _Float16* W2h = (_Float16*)(ws + 100663296);             //  16,777,216  W_out fp16 [2048,4096]
    _Float16* Hp  = (_Float16*)(ws + 117440512);             // 134,316,032  h fp16 [4*(4096+3),4096]
    _Float16* Yh  = (_Float16*)(ws + 251756544);             // 134,217,728  y fp16 [16384,4096]
    (void)ws_size; (void)in_sizes; (void)n_in; (void)out_size;

    cvt_f32_f16<<<32768, 256, 0, stream>>>(x,     Xh,  Mn * Hn / 4);
    cvt_f32_f16<<<8192,  256, 0, stream>>>(W_in,  W1h, CINn * Hn / 4);
    cvt_convw <<<8192,  256, 0, stream>>>(conv_w, Wch);
    cvt_f32_f16<<<8192,  256, 0, stream>>>(W_out, W2h, Hn * COUTn / 4);
    zero_pads <<<192,   256, 0, stream>>>(Hp);

    // stage 1: h = x @ W_in^T + b_in        -> Hp (padded, fp16)
    gemm8<0><<<(Mn / 256) * (CINn / 256), 512, 0, stream>>>(Xh, W1h, b_in, (void*)Hp, Hn, CINn / 256);
    // stage 2: y = silu(causal_gconv(h) + conv_b) -> Yh (fp16)
    gemm8<1><<<(Mn / 256) * (COUTn / 256), 512, 0, stream>>>(Hp, Wch, conv_b, (void*)Yh, GCn * Kt, COUTn / 256);
    // stage 3: out = y @ W_out^T + b_out    -> fp32
    gemm8<2><<<(Mn / 256) * (Hn / 256), 512, 0, stream>>>(Yh, W2h, b_out, (void*)out, COUTn, Hn / 256);
}

// Round 2
// 1049.390 us; speedup vs baseline: 1.3629x; 1.0347x over previous
//
#include <hip/hip_runtime.h>
#include <cstdint>
#include <cstddef>

// Problem constants
static constexpr int Bn   = 4;
static constexpr int Sn   = 4096;
static constexpr int Hn   = 2048;
static constexpr int CINn = 4096;
static constexpr int COUTn= 4096;
static constexpr int GCn  = 512;    // CIN/G
static constexpr int Kt   = 4;      // conv taps
static constexpr int Mn   = Bn * Sn;   // 16384
static constexpr int SPn  = Sn + 3;    // padded rows per batch (3 zero rows in front)

typedef _Float16 half8 __attribute__((ext_vector_type(8)));
typedef _Float16 half4 __attribute__((ext_vector_type(4)));
typedef float    floatx4 __attribute__((ext_vector_type(4)));

// ---------------- prep kernels ----------------

__global__ void cvt_f32_f16(const float* __restrict__ src, _Float16* __restrict__ dst, int n4) {
    int i = blockIdx.x * blockDim.x + threadIdx.x;
    if (i < n4) {
        float4 v = ((const float4*)src)[i];
        half4 h;
        h[0] = (_Float16)v.x; h[1] = (_Float16)v.y;
        h[2] = (_Float16)v.z; h[3] = (_Float16)v.w;
        ((half4*)dst)[i] = h;
    }
}

// conv_w [COUT, 512, 4] fp32 -> Wc [COUT, k*512 + ci] fp16
__global__ void cvt_convw(const float* __restrict__ src, _Float16* __restrict__ dst) {
    int t = blockIdx.x * blockDim.x + threadIdx.x;   // 0 .. 4096*512
    int co = t >> 9, ci = t & 511;
    float4 v = ((const float4*)src)[(co << 9) + ci]; // src[co][ci][0..3] contiguous
    size_t base = (size_t)co * 2048 + ci;
    dst[base]        = (_Float16)v.x;
    dst[base + 512]  = (_Float16)v.y;
    dst[base + 1024] = (_Float16)v.z;
    dst[base + 1536] = (_Float16)v.w;
}

// zero the 3 leading pad rows of each batch in Hp [B*(S+3), 4096]
__global__ void zero_pads(_Float16* __restrict__ Hp) {
    int t = blockIdx.x * blockDim.x + threadIdx.x;   // 4 * 3*4096 = 49152
    int b = t / (3 * CINn);
    int off = t - b * (3 * CINn);
    Hp[(size_t)b * SPn * CINn + off] = (_Float16)0.f;
}

// ---------------- 256x256 / BK=64 / 8-wave GEMM, register read-ahead ----------------
// C[m,n] = sum_k A[m,k]*B[n,k]  (B^T layout: K contiguous in both operands)
// MODE 0: stage1  A=Xh[16384,2048]            out: Hp fp16, padded rows, +b_in
// MODE 1: stage2  A=Hp (shifted conv gather)  out: Yh fp16, +conv_b, SiLU
// MODE 2: stage3  A=Yh[16384,4096]            out: fp32, +b_out
//
// v2 schedule (2 barriers + 1 vmcnt per K-tile; MFMA never waits on lgkm):
//   frag regs: afA = A-half0(t) [32v], afB = A-half1(t) [32v], bf = all B(t) [32v]
//   P1: read B1(t)->bf23      | MFMA(0,0) afA*bf01 | WL0 BAR | stage A0,B(t+2) [6]
//   P2: read A1(t)->afB       | MFMA(0,1) afA*bf23 | WV(6) WL0 BAR | stage A1(t+2) [2]
//   P3: read A0lo(t+1)->afA01 | MFMA(1,0) afB*bf01   (no barrier)
//   P4: read A0hi(t+1)->afA23, B0(t+1)->bf01 | MFMA(1,1) afB*bf23  (no barrier)
// Hazard proof: every region's readers drain at the WL0 preceding the BAR after
// which it is re-staged (A0/B0 read P3/P4(t-1) -> drained WL0(P1,t) -> staged
// post-BAR(P1,t); B1 read P1(t) ditto; A1 read P2(t) -> staged post-BAR(P2,t)).
// Reads of tile t+1 data occur after BAR(P2,t); WV(6)@P2(t) keeps only P1(t)'s 6
// newest loads -> everything staged <=P2(t-1) (i.e. ALL of t+1's data) retired,
// and the barrier publishes that to all waves. Tail (tt>=NT-2): stages skipped,
// WV(0) drains. Reads are plain C++ loads: backend emits fine-grained lgkmcnt
// for the MFMA deps of the NEXT phase (full phase of slack).

__device__ __forceinline__ void async16(const void* g, void* l) {
    __builtin_amdgcn_global_load_lds(
        (__attribute__((address_space(1))) void*)(g),
        (__attribute__((address_space(3))) void*)(l),
        16, 0, 0);
}

#define BAR()  __builtin_amdgcn_s_barrier()
#define SB0()  __builtin_amdgcn_sched_barrier(0)
#define WL0()  asm volatile("s_waitcnt lgkmcnt(0)" ::: "memory")
#define WV(n)  asm volatile("s_waitcnt vmcnt(" #n ")" ::: "memory")
#define PRIO1() __builtin_amdgcn_s_setprio(1)
#define PRIO0() __builtin_amdgcn_s_setprio(0)

template <int MODE>
__global__ __launch_bounds__(512, 2) void gemm8(
    const _Float16* __restrict__ A,
    const _Float16* __restrict__ Bw,
    const float* __restrict__ bias,
    void* __restrict__ outp,
    int Kd, int Ntiles)
{
    __shared__ __align__(16) _Float16 smem[2][2][256 * 64];   // [buf][A/B] 128 KiB

    const int t  = threadIdx.x;
    const int w  = t >> 6;        // wave 0..7
    const int l  = t & 63;
    const int wm = w >> 2;        // 2 wave rows
    const int wn = w & 3;         // 4 wave cols

    // bijective XCD swizzle (nwg % 8 == 0 for all stages)
    const int nwg = (int)gridDim.x;
    const int bid = (int)blockIdx.x;
    const int swz = (bid & 7) * (nwg >> 3) + (bid >> 3);
    const int mt = swz / Ntiles, nt = swz - mt * Ntiles;
    const int m0 = mt * 256, n0 = nt * 256;

    // --- staging addresses: thread t covers row (q*64 + t>>3), swizzled col block
    const int sr  = t >> 3;                        // 0..63
    const int scb = ((t & 7) ^ (sr & 7)) << 3;     // swizzled col, fp16 units
    const _Float16* pa0;
    if (MODE == 1) {
        // A row for (m, tap k): b*(S+3) + s + k ; col: g*512 + ci
        const int ma = m0 + sr;
        pa0 = A + ((size_t)((ma >> 12) * SPn + (ma & 4095)) << 12) + (n0 >> 9) * 512 + scb;
    } else {
        pa0 = A + (size_t)(m0 + sr) * Kd + scb;
    }
    const _Float16* pb0 = Bw + (size_t)(n0 + sr) * Kd + scb;
    // q-region strides (uniform: 256-row tiles never cross the 4096-row batch)
    const size_t aq = (MODE == 1) ? (size_t)(64 * 4096) : (size_t)64 * Kd;
    const size_t bq = (size_t)64 * Kd;
    const int wst = w * 512;      // wave-uniform LDS offset within a region (fp16)

    const int fr = l & 15, quad = l >> 4, sw = fr & 7;

    floatx4 acc[8][4] = {};
    half8 afA[4][2];   // A-half0(t): rows wm*128 + mf*16 + fr
    half8 afB[4][2];   // A-half1(t): rows wm*128 + 64 + mf*16 + fr
    half8 bf[4][2];    // B(t): rows wn*64 + (idx)*16 + fr ; bf[0..1]=B0, bf[2..3]=B1

    const int NT = Kd >> 6;

#define KADJ(kk) ((MODE == 1) ? ((kk) + (((kk) >> 9) * 3584)) : (kk))
#define STA(b, q, ko) async16(pa0 + (size_t)(q) * aq + (ko), &smem[b][0][(q) * 4096 + wst])
#define STB(b, q, ko) async16(pb0 + (size_t)(q) * bq + (ko), &smem[b][1][(q) * 4096 + wst])

#define LCOL(ks) ((((ks << 2) + quad) ^ sw) << 3)

#define RD_B0(cb) do { \
    _Pragma("unroll") for (int nf = 0; nf < 2; ++nf) \
    _Pragma("unroll") for (int ks = 0; ks < 2; ++ks) { \
        int row = wn * 64 + nf * 16 + fr; \
        bf[nf][ks] = *(const half8*)(&smem[cb][1][row * 64 + LCOL(ks)]); \
    } } while (0)

#define RD_B1(cb) do { \
    _Pragma("unroll") for (int nf = 0; nf < 2; ++nf) \
    _Pragma("unroll") for (int ks = 0; ks < 2; ++ks) { \
        int row = wn * 64 + 32 + nf * 16 + fr; \
        bf[2 + nf][ks] = *(const half8*)(&smem[cb][1][row * 64 + LCOL(ks)]); \
    } } while (0)

#define RD_A1(cb) do { \
    _Pragma("unroll") for (int mf = 0; mf < 4; ++mf) \
    _Pragma("unroll") for (int ks = 0; ks < 2; ++ks) { \
        int row = wm * 128 + 64 + mf * 16 + fr; \
        afB[mf][ks] = *(const half8*)(&smem[cb][0][row * 64 + LCOL(ks)]); \
    } } while (0)

#define RD_A0_LO(cb) do { \
    _Pragma("unroll") for (int mf = 0; mf < 2; ++mf) \
    _Pragma("unroll") for (int ks = 0; ks < 2; ++ks) { \
        int row = wm * 128 + mf * 16 + fr; \
        afA[mf][ks] = *(const half8*)(&smem[cb][0][row * 64 + LCOL(ks)]); \
    } } while (0)

#define RD_A0_HI(cb) do { \
    _Pragma("unroll") for (int mf = 2; mf < 4; ++mf) \
    _Pragma("unroll") for (int ks = 0; ks < 2; ++ks) { \
        int row = wm * 128 + mf * 16 + fr; \
        afA[mf][ks] = *(const half8*)(&smem[cb][0][row * 64 + LCOL(ks)]); \
    } } while (0)

// MMA_PH(AF, mh, nh): acc[mh*4+mf][nh*2+nf] += AF[mf][ks] * bf[nh*2+nf][ks]
#define MMA_PH(AF, mh, nh) do { \
    _Pragma("unroll") for (int mf = 0; mf < 4; ++mf) \
    _Pragma("unroll") for (int nf = 0; nf < 2; ++nf) \
    _Pragma("unroll") for (int ks = 0; ks < 2; ++ks) \
        acc[(mh) * 4 + mf][(nh) * 2 + nf] = __builtin_amdgcn_mfma_f32_16x16x32_f16( \
            AF[mf][ks], bf[(nh) * 2 + nf][ks], acc[(mh) * 4 + mf][(nh) * 2 + nf], 0, 0, 0); \
    } while (0)

    // --- prologue: tile0 -> buf0, tile1 -> buf1 (8 loads each)
    {
        STA(0, 0, 0); STA(0, 1, 0); STA(0, 2, 0); STA(0, 3, 0);
        STB(0, 0, 0); STB(0, 1, 0); STB(0, 2, 0); STB(0, 3, 0);
        const int ka1 = KADJ(64);
        STA(1, 0, ka1); STA(1, 1, ka1); STA(1, 2, ka1); STA(1, 3, ka1);
        STB(1, 0, 64); STB(1, 1, 64); STB(1, 2, 64); STB(1, 3, 64);
        WV(0); BAR(); SB0();
        // preload tile0 frags for P1/P2: afA = A0(0), bf01 = B0(0)
        RD_A0_LO(0); RD_A0_HI(0); RD_B0(0);
    }

    PRIO1();
    for (int tt = 0; tt < NT; ++tt) {
        const int cur = tt & 1, nxt = cur ^ 1;
        const bool s1 = (tt + 1 < NT), s2 = (tt + 2 < NT);
        const int ka2 = KADJ((tt + 2) << 6);
        const int kb2 = (tt + 2) << 6;

        // ---- P1 ----
        RD_B1(cur);
        MMA_PH(afA, 0, 0);
        PRIO0(); WL0(); BAR(); SB0(); PRIO1();
        if (s2) { STA(cur, 0, ka2); STA(cur, 2, ka2);
                  STB(cur, 0, kb2); STB(cur, 1, kb2); STB(cur, 2, kb2); STB(cur, 3, kb2); }

        // ---- P2 ----
        RD_A1(cur);
        MMA_PH(afA, 0, 1);
        PRIO0();
        if (s2) { WV(6); } else { WV(0); }
        WL0(); BAR(); SB0(); PRIO1();
        if (s2) { STA(cur, 1, ka2); STA(cur, 3, ka2); }

        // ---- P3 (no barrier) ----
        if (s1) RD_A0_LO(nxt);
        MMA_PH(afB, 1, 0);

        // ---- P4 (no barrier) ----
        if (s1) { RD_A0_HI(nxt); RD_B0(nxt); }
        MMA_PH(afB, 1, 1);
    }
    PRIO0();

    // --- epilogue: D[row=(l>>4)*4+r][col=l&15] per 16x16 subtile ---
    #pragma unroll
    for (int nf = 0; nf < 4; ++nf) {
        const int ncol = n0 + wn * 64 + nf * 16 + fr;
        const float bv = bias[ncol];
        #pragma unroll
        for (int mf = 0; mf < 8; ++mf) {
            const int mb = m0 + wm * 128 + mf * 16 + quad * 4;
            #pragma unroll
            for (int r = 0; r < 4; ++r) {
                const int m = mb + r;
                float v = acc[mf][nf][r] + bv;
                if (MODE == 0) {
                    const size_t row = (size_t)((m >> 12) * SPn + 3 + (m & 4095));
                    ((_Float16*)outp)[(row << 12) + ncol] = (_Float16)v;
                } else if (MODE == 1) {
                    v = v * (1.0f / (1.0f + __expf(-v)));   // SiLU
                    ((_Float16*)outp)[((size_t)m << 12) + ncol] = (_Float16)v;
                } else {
                    ((float*)outp)[((size_t)m << 11) + ncol] = v;
                }
            }
        }
    }
#undef KADJ
#undef STA
#undef STB
#undef LCOL
#undef RD_B0
#undef RD_B1
#undef RD_A1
#undef RD_A0_LO
#undef RD_A0_HI
#undef MMA_PH
}

// ---------------- launch ----------------

extern "C" void kernel_launch(void* const* d_in, const int* in_sizes, int n_in,
                              void* d_out, int out_size, void* d_ws, size_t ws_size,
                              hipStream_t stream) {
    const float* x      = (const float*)d_in[0];
    const float* W_in   = (const float*)d_in[1];
    const float* b_in   = (const float*)d_in[2];
    const float* conv_w = (const float*)d_in[3];
    const float* conv_b = (const float*)d_in[4];
    const float* W_out  = (const float*)d_in[5];
    const float* b_out  = (const float*)d_in[6];
    float* out = (float*)d_out;

    // workspace layout (bytes) — total ~368 MB
    char* ws = (char*)d_ws;
    _Float16* Xh  = (_Float16*)(ws);                         //  67,108,864  x fp16 [16384,2048]
    _Float16* W1h = (_Float16*)(ws + 67108864);              //  16,777,216  W_in fp16 [4096,2048]
    _Float16* Wch = (_Float16*)(ws + 83886080);              //  16,777,216  conv_w fp16 [4096,2048]
    _Float16* W2h = (_Float16*)(ws + 100663296);             //  16,777,216  W_out fp16 [2048,4096]
    _Float16* Hp  = (_Float16*)(ws + 117440512);             // 134,316,032  h fp16 [4*(4096+3),4096]
    _Float16* Yh  = (_Float16*)(ws + 251756544);             // 134,217,728  y fp16 [16384,4096]
    (void)ws_size; (void)in_sizes; (void)n_in; (void)out_size;

    cvt_f32_f16<<<32768, 256, 0, stream>>>(x,     Xh,  Mn * Hn / 4);
    cvt_f32_f16<<<8192,  256, 0, stream>>>(W_in,  W1h, CINn * Hn / 4);
    cvt_convw <<<8192,  256, 0, stream>>>(conv_w, Wch);
    cvt_f32_f16<<<8192,  256, 0, stream>>>(W_out, W2h, Hn * COUTn / 4);
    zero_pads <<<192,   256, 0, stream>>>(Hp);

    // stage 1: h = x @ W_in^T + b_in        -> Hp (padded, fp16)
    gemm8<0><<<(Mn / 256) * (CINn / 256), 512, 0, stream>>>(Xh, W1h, b_in, (void*)Hp, Hn, CINn / 256);
    // stage 2: y = silu(causal_gconv(h) + conv_b) -> Yh (fp16)
    gemm8<1><<<(Mn / 256) * (COUTn / 256), 512, 0, stream>>>(Hp, Wch, conv_b, (void*)Yh, GCn * Kt, COUTn / 256);
    // stage 3: out = y @ W_out^T + b_out    -> fp32
    gemm8<2><<<(Mn / 256) * (Hn / 256), 512, 0, stream>>>(Yh, W2h, b_out, (void*)out, COUTn, Hn / 256);
}